// Round 8
// baseline (466.890 us; speedup 1.0000x reference)
//
#include <hip/hip_runtime.h>
#include <cstdint>

#define BATCH 4
#define NPTS  8192
#define KNN   5
#define CAPQ  176

typedef short bf16x8 __attribute__((ext_vector_type(8)));
typedef float f32x4  __attribute__((ext_vector_type(4)));
#define MFMA16(a, b, c) __builtin_amdgcn_mfma_f32_16x16x32_bf16((a), (b), (c), 0, 0, 0)

__device__ __forceinline__ unsigned short f2bf(float x) {
    unsigned u = __float_as_uint(x);
    unsigned r = u + 0x7fffu + ((u >> 16) & 1u);   // RN-even
    return (unsigned short)(r >> 16);
}
__device__ __forceinline__ float bf2f(unsigned short h) {
    return __uint_as_float(((unsigned)h) << 16);
}

// ---------------------------------------------------------------------------
// Kernel W: split w3/w4/w5 into bf16 hi/lo pairs (fp32-emulation operands)
// + precompute |c|^2 for every point (c2, used by knn's dot-form distance).
// ---------------------------------------------------------------------------
__global__ __launch_bounds__(256) void wsplit_kernel(
        const float* __restrict__ w3, const float* __restrict__ w4,
        const float* __restrict__ w5, const float* __restrict__ x,
        unsigned short* __restrict__ w3H, unsigned short* __restrict__ w3L,
        unsigned short* __restrict__ w4H, unsigned short* __restrict__ w4L,
        unsigned short* __restrict__ w5H, unsigned short* __restrict__ w5L,
        float* __restrict__ c2) {
    const int i = blockIdx.x * 256 + threadIdx.x;   // 335872 total, exact grid
    if (i >= 303104) {                              // 32768 point-norm entries
        const int pt = i - 303104;
        const int b = pt >> 13, n = pt & 8191;
        const float* xb = x + (size_t)b * 3 * NPTS;
        const float cx = xb[n], cy = xb[NPTS + n], cz = xb[2 * NPTS + n];
        c2[pt] = fmaf(cz, cz, fmaf(cy, cy, cx * cx));
        return;
    }
    const float* src; unsigned short *dh, *dl; int off;
    if (i < 8192)       { src = w3; dh = w3H; dl = w3L; off = i; }
    else if (i < 40960) { src = w4; dh = w4H; dl = w4L; off = i - 8192; }
    else                { src = w5; dh = w5H; dl = w5L; off = i - 40960; }
    const float v = src[off];
    const unsigned short hi = f2bf(v);
    dh[off] = hi;
    dl[off] = f2bf(v - bf2f(hi));
}

// ---------------------------------------------------------------------------
// Kernel A: exact 5-NN, v11 (half-subset threshold pass).
// Pass A builds the per-query threshold from only the FIRST 256 of each
// wave's 512-candidate slice (pair-min top-5 chain, as v10). Validity: a
// threshold from ANY candidate subset is >= the true 5th distance (k-th
// order statistic grows as samples shrink), and the 5 smallest pair-mins
// are actual distances of 5 distinct candidates -> slice-5th-of-pairmins
// upper-bounds the global 5th. Subset only RAISES the threshold: no true
// neighbor can be missed. Cost: more accepts -- E~20/query, sigma~12;
// CAPQ=176 is ~13 sigma of headroom (P(overflow) ~ e^-80 on random data).
// Pass B (full 8192-candidate scan, exact acceptance) and pass C (exact
// fp64 re-rank, 4 phases x 16 queries) unchanged. Margin 4e-4 > 2x fp32
// error. 16 waves/block, 32 waves/CU, LDS-staged broadcast reads (v8).
// ---------------------------------------------------------------------------
__global__ __launch_bounds__(1024, 8) void knn_kernel(const float* __restrict__ x,
                                                      const float* __restrict__ c2,
                                                      int* __restrict__ idx_out) {
    __shared__ __align__(16) char sbuf[32768];  // stage[16][128] f4 / qd union
    __shared__ __align__(16) char buf2[45056];  // qidx[64*176] (thrA aliases 4KB)
    __shared__ float  thrQ[64];         //  per-query threshold
    __shared__ int    qcnt[64];

    float* thrA = (float*)buf2;         // [16][64] slice 5th-of-pairmins
    int*   qidx = (int*)buf2;           // [64][CAPQ] finalist indices

    const int t = threadIdx.x;
    const int lane = t & 63;            // query lane
    const int s = t >> 6;               // slice 0..15 (wave-uniform)
    const int b = blockIdx.x >> 7;
    const int q0 = (blockIdx.x & 127) * 64;
    const int qg = q0 + lane;
    const float* xb = x + (size_t)b * 3 * NPTS;

    float4* stw = ((float4*)sbuf) + s * 128;   // wave-private 2KB stage
    double* qd  = (double*)sbuf;               // pass-C alias (stage dead then)

    const float nqx = -2.0f * xb[qg];
    const float nqy = -2.0f * xb[NPTS + qg];
    const float nqz = -2.0f * xb[2 * NPTS + qg];

    if (t < 64) qcnt[t] = 0;

    const float2* gx = (const float2*)xb;
    const float2* gy = (const float2*)(xb + NPTS);
    const float2* gz = (const float2*)(xb + 2 * NPTS);
    const float2* gc = (const float2*)(c2 + b * NPTS);
    const int f2base = s * 256;         // float2-group base of this slice

    // ---- Pass A: top-5 of pair minima over HALF the slice (256 cands) ----
    float s0 = 3e38f, s1 = 3e38f, s2 = 3e38f, s3 = 3e38f, s4 = 3e38f;
    {
        float2 xv = gx[f2base + lane], yv = gy[f2base + lane];
        float2 zv = gz[f2base + lane], cv = gc[f2base + lane];
        for (int ch = 0; ch < 2; ++ch) {
            stw[0 * 64 + lane] = make_float4(xv.x, yv.x, zv.x, cv.x);
            stw[1 * 64 + lane] = make_float4(xv.y, yv.y, zv.y, cv.y);
            if (ch < 1) {               // prefetch next chunk under compute
                const int f2 = f2base + (ch + 1) * 64 + lane;
                xv = gx[f2]; yv = gy[f2]; zv = gz[f2]; cv = gc[f2];
            }
            for (int u4 = 0; u4 < 32; ++u4) {
                float4 cd[4];
                #pragma unroll
                for (int j = 0; j < 4; ++j) cd[j] = stw[u4 * 4 + j];
                float d[4];
                #pragma unroll
                for (int j = 0; j < 4; ++j)
                    d[j] = fmaf(cd[j].x, nqx,
                           fmaf(cd[j].y, nqy, fmaf(cd[j].z, nqz, cd[j].w)));
                const float m0 = fminf(d[0], d[1]);
                const float m1 = fminf(d[2], d[3]);
                s4 = __builtin_amdgcn_fmed3f(s3, m0, s4);
                s3 = __builtin_amdgcn_fmed3f(s2, m0, s3);
                s2 = __builtin_amdgcn_fmed3f(s1, m0, s2);
                s1 = __builtin_amdgcn_fmed3f(s0, m0, s1);
                s0 = fminf(s0, m0);
                s4 = __builtin_amdgcn_fmed3f(s3, m1, s4);
                s3 = __builtin_amdgcn_fmed3f(s2, m1, s3);
                s2 = __builtin_amdgcn_fmed3f(s1, m1, s2);
                s1 = __builtin_amdgcn_fmed3f(s0, m1, s1);
                s0 = fminf(s0, m1);
            }
        }
    }
    thrA[s * 64 + lane] = s4;
    __syncthreads();
    if (t < 64) {
        float m = thrA[t];
        #pragma unroll
        for (int ww = 1; ww < 16; ++ww) m = fminf(m, thrA[ww * 64 + t]);
        thrQ[t] = m + 4e-4f;            // margin > 2x worst-case fp32 error
    }
    __syncthreads();                    // thrA dead; qidx alias live below

    // ---- Pass B: compact accepted candidate indices per query (full scan) --
    const float thrq = thrQ[lane];
    {
        float2 xv = gx[f2base + lane], yv = gy[f2base + lane];
        float2 zv = gz[f2base + lane], cv = gc[f2base + lane];
        for (int ch = 0; ch < 4; ++ch) {
            const int cb = s * 512 + ch * 128;    // chunk candidate base
            stw[0 * 64 + lane] = make_float4(xv.x, yv.x, zv.x, cv.x);
            stw[1 * 64 + lane] = make_float4(xv.y, yv.y, zv.y, cv.y);
            if (ch < 3) {
                const int f2 = f2base + (ch + 1) * 64 + lane;
                xv = gx[f2]; yv = gy[f2]; zv = gz[f2]; cv = gc[f2];
            }
            for (int u4 = 0; u4 < 32; ++u4) {
                float4 cd[4];
                #pragma unroll
                for (int j = 0; j < 4; ++j) cd[j] = stw[u4 * 4 + j];
                float d[4];
                #pragma unroll
                for (int j = 0; j < 4; ++j)
                    d[j] = fmaf(cd[j].x, nqx,
                           fmaf(cd[j].y, nqy, fmaf(cd[j].z, nqz, cd[j].w)));
                const float dmin = fminf(fminf(d[0], d[1]), fminf(d[2], d[3]));
                if (dmin < thrq) {
                    #pragma unroll
                    for (int j = 0; j < 4; ++j) {
                        if (d[j] < thrq) {
                            const int slot = atomicAdd(&qcnt[lane], 1);
                            const int u = u4 * 4 + j;
                            const int gid = cb + 2 * (u & 63) + (u >> 6);
                            if (slot < CAPQ) qidx[lane * CAPQ + slot] = gid;
                        }
                    }
                }
            }
        }
    }

    // ---- Pass C: exact fp64 distances + lexicographic rank select ----
    // 4 phases of 16 queries (qd alias fits 32KB stage); 64 threads/query.
    const int qll = t >> 6;               // 0..15 (local query)
    const int jt = t & 63;
    for (int ph = 0; ph < 4; ++ph) {
        __syncthreads();                  // stage/qd region handoff
        const int ql = ph * 16 + qll;
        const int cnt = min(qcnt[ql], CAPQ);
        const double Qx = (double)xb[q0 + ql];
        const double Qy = (double)xb[NPTS + q0 + ql];
        const double Qz = (double)xb[2 * NPTS + q0 + ql];
        for (int j = jt; j < cnt; j += 64) {
            const int ci = qidx[ql * CAPQ + j];
            const double ddx = Qx - (double)xb[ci];
            const double ddy = Qy - (double)xb[NPTS + ci];
            const double ddz = Qz - (double)xb[2 * NPTS + ci];
            qd[qll * CAPQ + j] = ddx * ddx + ddy * ddy + ddz * ddz;
        }
        __syncthreads();
        for (int j = jt; j < cnt; j += 64) {
            const double dj = qd[qll * CAPQ + j];
            const int    ij = qidx[ql * CAPQ + j];
            int rank = 0;
            for (int k = 0; k < cnt; ++k) {
                const double dk = qd[qll * CAPQ + k];
                const int    ik = qidx[ql * CAPQ + k];
                rank += (dk < dj) || (dk == dj && ik < ij);
            }
            if (rank < KNN)
                idx_out[((size_t)b * NPTS + q0 + ql) * KNN + rank] = ij;
        }
    }
}

// ---------------------------------------------------------------------------
// Kernel B1: gather + L1 (6->64) + x1max + L2 (64->64) + x2max (fp32 compute).
// Epilogue writes h2 as interleaved bf16 hi|lo rows (d_out scratch) and
// x1/x2 into catH/catL.
// ---------------------------------------------------------------------------
__global__ __launch_bounds__(256) void mlp12_kernel(const float* __restrict__ x,
                                                    const int* __restrict__ idx,
                                                    const float* __restrict__ w1,
                                                    const float* __restrict__ w2,
                                                    unsigned short* __restrict__ h2HL,
                                                    unsigned short* __restrict__ catH,
                                                    unsigned short* __restrict__ catL) {
    __shared__ float w1s[64 * 6];
    __shared__ float w2s[64 * 68];
    __shared__ float fbuf[80][6];
    __shared__ float h1s[80 * 68];
    __shared__ float h2s[80 * 68];
    const int t = threadIdx.x;
    const int pbase = blockIdx.x * 16;

    for (int i = t; i < 384; i += 256) w1s[i] = w1[i];
    for (int i = t; i < 4096; i += 256) {
        int c = i >> 6, q = i & 63;
        w2s[c * 68 + q] = w2[i];
    }
    if (t < 80) {
        const int pt = pbase + t / 5;
        const int b = pt >> 13;
        const int n = pt & 8191;
        const int k = t % 5;
        const int j = idx[(size_t)pt * KNN + k];
        const float* xb = x + (size_t)b * 3 * NPTS;
        fbuf[t][0] = xb[j];
        fbuf[t][1] = xb[NPTS + j];
        fbuf[t][2] = xb[2 * NPTS + j];
        fbuf[t][3] = xb[n];
        fbuf[t][4] = xb[NPTS + n];
        fbuf[t][5] = xb[2 * NPTS + n];
    }
    __syncthreads();

    for (int o = t; o < 5120; o += 256) {
        const int r = o >> 6, c = o & 63;
        float acc = 0.f;
        #pragma unroll
        for (int q = 0; q < 6; ++q) acc = fmaf(w1s[c * 6 + q], fbuf[r][q], acc);
        h1s[r * 68 + c] = fmaxf(acc, 0.f);
    }
    __syncthreads();

    for (int o = t; o < 1024; o += 256) {
        const int p = o >> 6, c = o & 63;
        float m = h1s[(p * 5) * 68 + c];
        #pragma unroll
        for (int k = 1; k < 5; ++k) m = fmaxf(m, h1s[(p * 5 + k) * 68 + c]);
        const unsigned short hi = f2bf(m);
        const size_t co = (size_t)(pbase + p) * 512 + c;
        catH[co] = hi;
        catL[co] = f2bf(m - bf2f(hi));
    }

    for (int tile = t; tile < 320; tile += 256) {
        const int r0 = (tile % 20) * 4;
        const int c0 = (tile / 20) * 4;
        float acc[4][4] = {};
        for (int q = 0; q < 64; q += 4) {
            float4 a[4], w[4];
            #pragma unroll
            for (int i = 0; i < 4; ++i) a[i] = *(const float4*)&h1s[(r0 + i) * 68 + q];
            #pragma unroll
            for (int j = 0; j < 4; ++j) w[j] = *(const float4*)&w2s[(c0 + j) * 68 + q];
            #pragma unroll
            for (int i = 0; i < 4; ++i)
                #pragma unroll
                for (int j = 0; j < 4; ++j) {
                    acc[i][j] = fmaf(a[i].x, w[j].x, acc[i][j]);
                    acc[i][j] = fmaf(a[i].y, w[j].y, acc[i][j]);
                    acc[i][j] = fmaf(a[i].z, w[j].z, acc[i][j]);
                    acc[i][j] = fmaf(a[i].w, w[j].w, acc[i][j]);
                }
        }
        #pragma unroll
        for (int i = 0; i < 4; ++i)
            #pragma unroll
            for (int j = 0; j < 4; ++j)
                h2s[(r0 + i) * 68 + c0 + j] = fmaxf(acc[i][j], 0.f);
    }
    __syncthreads();

    for (int o = t; o < 1024; o += 256) {
        const int p = o >> 6, c = o & 63;
        float m = h2s[(p * 5) * 68 + c];
        #pragma unroll
        for (int k = 1; k < 5; ++k) m = fmaxf(m, h2s[(p * 5 + k) * 68 + c]);
        const unsigned short hi = f2bf(m);
        const size_t co = (size_t)(pbase + p) * 512 + 64 + c;
        catH[co] = hi;
        catL[co] = f2bf(m - bf2f(hi));
    }
    for (int o = t; o < 5120; o += 256) {
        const int r = o >> 6, c = o & 63;
        const float v = h2s[r * 68 + c];
        const unsigned short hi = f2bf(v);
        const size_t rowb = (size_t)(pbase * 5 + r) * 128;
        h2HL[rowb + c]      = hi;
        h2HL[rowb + 64 + c] = f2bf(v - bf2f(hi));
    }
}

// ---------------------------------------------------------------------------
// Kernel B2: L3 (64->128) via split-bf16 MFMA + x3max.
// ---------------------------------------------------------------------------
__global__ __launch_bounds__(256) void mlp3_kernel(
        const unsigned short* __restrict__ h2HL,
        const unsigned short* __restrict__ w3H, const unsigned short* __restrict__ w3L,
        unsigned short* __restrict__ h3H, unsigned short* __restrict__ h3L,
        unsigned short* __restrict__ catH, unsigned short* __restrict__ catL) {
    __shared__ __align__(16) char smem[59904];
    unsigned short* aH = (unsigned short*)smem;            // [80][72]
    unsigned short* aL = aH + 80 * 72;                     // @11520B
    unsigned short* bH = (unsigned short*)(smem + 23040);  // [128][72]
    unsigned short* bL = (unsigned short*)(smem + 41472);

    const int t = threadIdx.x;
    const int R0 = blockIdx.x * 80;
    const int P0 = blockIdx.x * 16;

    for (int c = t; c < 1280; c += 256) {                  // A: h2 hi|lo rows
        const int row = c >> 4, seg = c & 15;
        const uint4 v = *(const uint4*)(h2HL + (size_t)(R0 + row) * 128 + seg * 8);
        *(uint4*)((seg < 8 ? aH : aL) + row * 72 + (seg & 7) * 8) = v;
    }
    for (int c = t; c < 1024; c += 256) {                  // B hi
        const int row = c >> 3, seg = c & 7;
        *(uint4*)(bH + row * 72 + seg * 8) =
            *(const uint4*)(w3H + row * 64 + seg * 8);
    }
    for (int c = t; c < 1024; c += 256) {                  // B lo
        const int row = c >> 3, seg = c & 7;
        *(uint4*)(bL + row * 72 + seg * 8) =
            *(const uint4*)(w3L + row * 64 + seg * 8);
    }
    __syncthreads();

    const int w = t >> 6, lane = t & 63;
    const int q = lane >> 4, l16 = lane & 15;
    const int n0 = w * 32;

    f32x4 acc[5][2];
    #pragma unroll
    for (int mt = 0; mt < 5; ++mt)
        #pragma unroll
        for (int nt = 0; nt < 2; ++nt)
            acc[mt][nt] = (f32x4){0.f, 0.f, 0.f, 0.f};

    #pragma unroll
    for (int kt = 0; kt < 2; ++kt) {
        const int k0 = kt * 32 + q * 8;
        bf16x8 bh[2], bl[2];
        #pragma unroll
        for (int nt = 0; nt < 2; ++nt) {
            bh[nt] = *(const bf16x8*)(bH + (n0 + nt * 16 + l16) * 72 + k0);
            bl[nt] = *(const bf16x8*)(bL + (n0 + nt * 16 + l16) * 72 + k0);
        }
        #pragma unroll
        for (int mt = 0; mt < 5; ++mt) {
            const bf16x8 ah = *(const bf16x8*)(aH + (mt * 16 + l16) * 72 + k0);
            const bf16x8 al = *(const bf16x8*)(aL + (mt * 16 + l16) * 72 + k0);
            #pragma unroll
            for (int nt = 0; nt < 2; ++nt) {
                acc[mt][nt] = MFMA16(ah, bh[nt], acc[mt][nt]);
                acc[mt][nt] = MFMA16(ah, bl[nt], acc[mt][nt]);
                acc[mt][nt] = MFMA16(al, bh[nt], acc[mt][nt]);
            }
        }
    }

    __syncthreads();                       // A/B staging dead; alias Dbuf
    float* Dbuf = (float*)smem;            // [80][132] fp32
    #pragma unroll
    for (int mt = 0; mt < 5; ++mt)
        #pragma unroll
        for (int nt = 0; nt < 2; ++nt)
            #pragma unroll
            for (int r = 0; r < 4; ++r)
                Dbuf[(mt * 16 + q * 4 + r) * 132 + n0 + nt * 16 + l16] =
                    fmaxf(acc[mt][nt][r], 0.f);
    __syncthreads();

    {
        const int col = t & 127;
        const int p0 = (t >> 7) * 8;
        #pragma unroll
        for (int p = 0; p < 8; ++p) {
            const int pp = p0 + p;
            float mx = 0.f;
            #pragma unroll
            for (int k = 0; k < 5; ++k) {
                const int row = pp * 5 + k;
                const float v = Dbuf[row * 132 + col];
                const unsigned short hi = f2bf(v);
                const unsigned short lo = f2bf(v - bf2f(hi));
                const size_t off = (size_t)(R0 + row) * 128 + col;
                h3H[off] = hi;
                h3L[off] = lo;
                mx = fmaxf(mx, bf2f(hi) + bf2f(lo));
            }
            const unsigned short mh = f2bf(mx);
            const size_t co = (size_t)(P0 + pp) * 512 + 128 + col;
            catH[co] = mh;
            catL[co] = f2bf(mx - bf2f(mh));
        }
    }
}

// ---------------------------------------------------------------------------
// Kernel C: L4 (128->256) via split-bf16 MFMA + x4max.
// ---------------------------------------------------------------------------
__global__ __launch_bounds__(256) void mlp4_kernel(
        const unsigned short* __restrict__ h3H, const unsigned short* __restrict__ h3L,
        const unsigned short* __restrict__ w4H, const unsigned short* __restrict__ w4L,
        unsigned short* __restrict__ catH, unsigned short* __restrict__ catL) {
    __shared__ __align__(16) char smem[64000];
    unsigned short* aH = (unsigned short*)smem;            // [80][136]
    unsigned short* aL = aH + 80 * 136;                    // @21760B
    unsigned short* bH = (unsigned short*)(smem + 43520);  // [128][40] per k-step
    unsigned short* bL = (unsigned short*)(smem + 53760);

    const int t = threadIdx.x;
    const int R0 = blockIdx.x * 80;
    const int P0 = blockIdx.x * 16;
    const int ny = blockIdx.y;                             // cout half

    for (int c = t; c < 1280; c += 256) {                  // A hi
        const int row = c >> 4, seg = c & 15;
        *(uint4*)(aH + row * 136 + seg * 8) =
            *(const uint4*)(h3H + (size_t)(R0 + row) * 128 + seg * 8);
    }
    for (int c = t; c < 1280; c += 256) {                  // A lo
        const int row = c >> 4, seg = c & 15;
        *(uint4*)(aL + row * 136 + seg * 8) =
            *(const uint4*)(h3L + (size_t)(R0 + row) * 128 + seg * 8);
    }

    const int w = t >> 6, lane = t & 63;
    const int q = lane >> 4, l16 = lane & 15;
    const int n0 = w * 32;

    f32x4 acc[5][2];
    #pragma unroll
    for (int mt = 0; mt < 5; ++mt)
        #pragma unroll
        for (int nt = 0; nt < 2; ++nt)
            acc[mt][nt] = (f32x4){0.f, 0.f, 0.f, 0.f};

    for (int ks = 0; ks < 4; ++ks) {
        __syncthreads();
        #pragma unroll
        for (int i = 0; i < 2; ++i) {                      // B hi: 512 chunks
            const int c = t + i * 256;
            const int row = c >> 2, seg = c & 3;
            *(uint4*)(bH + row * 40 + seg * 8) =
                *(const uint4*)(w4H + (size_t)(ny * 128 + row) * 128 + ks * 32 + seg * 8);
        }
        #pragma unroll
        for (int i = 0; i < 2; ++i) {                      // B lo
            const int c = t + i * 256;
            const int row = c >> 2, seg = c & 3;
            *(uint4*)(bL + row * 40 + seg * 8) =
                *(const uint4*)(w4L + (size_t)(ny * 128 + row) * 128 + ks * 32 + seg * 8);
        }
        __syncthreads();

        const int k0 = ks * 32 + q * 8;
        const int kb = q * 8;
        bf16x8 bh[2], bl[2];
        #pragma unroll
        for (int nt = 0; nt < 2; ++nt) {
            bh[nt] = *(const bf16x8*)(bH + (n0 + nt * 16 + l16) * 40 + kb);
            bl[nt] = *(const bf16x8*)(bL + (n0 + nt * 16 + l16) * 40 + kb);
        }
        #pragma unroll
        for (int mt = 0; mt < 5; ++mt) {
            const bf16x8 ah = *(const bf16x8*)(aH + (mt * 16 + l16) * 136 + k0);
            const bf16x8 al = *(const bf16x8*)(aL + (mt * 16 + l16) * 136 + k0);
            #pragma unroll
            for (int nt = 0; nt < 2; ++nt) {
                acc[mt][nt] = MFMA16(ah, bh[nt], acc[mt][nt]);
                acc[mt][nt] = MFMA16(ah, bl[nt], acc[mt][nt]);
                acc[mt][nt] = MFMA16(al, bh[nt], acc[mt][nt]);
            }
        }
    }

    __syncthreads();
    float* Dbuf = (float*)smem;            // [80][132] fp32
    #pragma unroll
    for (int mt = 0; mt < 5; ++mt)
        #pragma unroll
        for (int nt = 0; nt < 2; ++nt)
            #pragma unroll
            for (int r = 0; r < 4; ++r)
                Dbuf[(mt * 16 + q * 4 + r) * 132 + n0 + nt * 16 + l16] =
                    fmaxf(acc[mt][nt][r], 0.f);
    __syncthreads();

    {
        const int col = t & 127;
        const int p0 = (t >> 7) * 8;
        const int cout = 256 + ny * 128 + col;
        #pragma unroll
        for (int p = 0; p < 8; ++p) {
            const int pp = p0 + p;
            float mx = 0.f;
            #pragma unroll
            for (int k = 0; k < 5; ++k)
                mx = fmaxf(mx, Dbuf[(pp * 5 + k) * 132 + col]);
            const unsigned short mh = f2bf(mx);
            const size_t co = (size_t)(P0 + pp) * 512 + cout;
            catH[co] = mh;
            catL[co] = f2bf(mx - bf2f(mh));
        }
    }
}

// ---------------------------------------------------------------------------
// Kernel D: final GEMM out = relu(cat(32768x512) * W5^T) via split-bf16 MFMA.
// ---------------------------------------------------------------------------
__global__ __launch_bounds__(256) void gemm512_kernel(
        const unsigned short* __restrict__ catH, const unsigned short* __restrict__ catL,
        const unsigned short* __restrict__ w5H, const unsigned short* __restrict__ w5L,
        float* __restrict__ out) {
    __shared__ __align__(16) char smem[40960];
    unsigned short* aH = (unsigned short*)smem;            // [128][40]
    unsigned short* aL = aH + 128 * 40;                    // @10240B
    unsigned short* bH = (unsigned short*)(smem + 20480);
    unsigned short* bL = (unsigned short*)(smem + 30720);

    const int t = threadIdx.x;
    const int m0 = blockIdx.x * 128;
    const int n0blk = blockIdx.y * 128;

    const int w = t >> 6, lane = t & 63;
    const int q = lane >> 4, l16 = lane & 15;
    const int m_off = (w >> 1) * 64;
    const int n_off = (w & 1) * 64;

    f32x4 acc[4][4];
    #pragma unroll
    for (int mt = 0; mt < 4; ++mt)
        #pragma unroll
        for (int nt = 0; nt < 4; ++nt)
            acc[mt][nt] = (f32x4){0.f, 0.f, 0.f, 0.f};

    for (int kc = 0; kc < 512; kc += 32) {
        __syncthreads();
        #pragma unroll
        for (int i = 0; i < 2; ++i) {
            const int c = t + i * 256;
            const int row = c >> 2, seg = c & 3;
            *(uint4*)(aH + row * 40 + seg * 8) =
                *(const uint4*)(catH + (size_t)(m0 + row) * 512 + kc + seg * 8);
        }
        #pragma unroll
        for (int i = 0; i < 2; ++i) {
            const int c = t + i * 256;
            const int row = c >> 2, seg = c & 3;
            *(uint4*)(aL + row * 40 + seg * 8) =
                *(const uint4*)(catL + (size_t)(m0 + row) * 512 + kc + seg * 8);
        }
        #pragma unroll
        for (int i = 0; i < 2; ++i) {
            const int c = t + i * 256;
            const int row = c >> 2, seg = c & 3;
            *(uint4*)(bH + row * 40 + seg * 8) =
                *(const uint4*)(w5H + (size_t)(n0blk + row) * 512 + kc + seg * 8);
        }
        #pragma unroll
        for (int i = 0; i < 2; ++i) {
            const int c = t + i * 256;
            const int row = c >> 2, seg = c & 3;
            *(uint4*)(bL + row * 40 + seg * 8) =
                *(const uint4*)(w5L + (size_t)(n0blk + row) * 512 + kc + seg * 8);
        }
        __syncthreads();

        const int k0 = q * 8;
        bf16x8 bh[4], bl[4];
        #pragma unroll
        for (int nt = 0; nt < 4; ++nt) {
            bh[nt] = *(const bf16x8*)(bH + (n_off + nt * 16 + l16) * 40 + k0);
            bl[nt] = *(const bf16x8*)(bL + (n_off + nt * 16 + l16) * 40 + k0);
        }
        #pragma unroll
        for (int mt = 0; mt < 4; ++mt) {
            const bf16x8 ah = *(const bf16x8*)(aH + (m_off + mt * 16 + l16) * 40 + k0);
            const bf16x8 al = *(const bf16x8*)(aL + (m_off + mt * 16 + l16) * 40 + k0);
            #pragma unroll
            for (int nt = 0; nt < 4; ++nt) {
                acc[mt][nt] = MFMA16(ah, bh[nt], acc[mt][nt]);
                acc[mt][nt] = MFMA16(ah, bl[nt], acc[mt][nt]);
                acc[mt][nt] = MFMA16(al, bh[nt], acc[mt][nt]);
            }
        }
    }

    // band-wise epilogue: 8 bands of 16 rows; LDS transpose for coalesced out
    float* bandbuf = (float*)smem;         // [16][132] fp32
    for (int b8 = 0; b8 < 8; ++b8) {
        __syncthreads();
        if ((w >> 1) == (b8 >> 2)) {
            const int mt = b8 & 3;
            #pragma unroll
            for (int nt = 0; nt < 4; ++nt)
                #pragma unroll
                for (int r = 0; r < 4; ++r)
                    bandbuf[(q * 4 + r) * 132 + n_off + nt * 16 + l16] =
                        fmaxf(acc[mt][nt][r], 0.f);
        }
        __syncthreads();
        const int col = t >> 1;
        const int ph = (t & 1) * 8;
        const int P = m0 + b8 * 16 + ph;
        const int bb = P >> 13, nn = P & 8191;
        const int cout = n0blk + col;
        float tmp[8];
        #pragma unroll
        for (int j = 0; j < 8; ++j) tmp[j] = bandbuf[(ph + j) * 132 + col];
        float* op = &out[((size_t)bb * 512 + cout) * NPTS + nn];
        *(float4*)op       = make_float4(tmp[0], tmp[1], tmp[2], tmp[3]);
        *(float4*)(op + 4) = make_float4(tmp[4], tmp[5], tmp[6], tmp[7]);
    }
}

extern "C" void kernel_launch(void* const* d_in, const int* in_sizes, int n_in,
                              void* d_out, int out_size, void* d_ws, size_t ws_size,
                              hipStream_t stream) {
    (void)in_sizes; (void)n_in; (void)out_size; (void)ws_size;
    const float* x  = (const float*)d_in[0];
    const float* w1 = (const float*)d_in[1];
    const float* w2 = (const float*)d_in[2];
    const float* w3 = (const float*)d_in[3];
    const float* w4 = (const float*)d_in[4];
    const float* w5 = (const float*)d_in[5];
    float* out = (float*)d_out;

    // workspace layout (111.3 MB total, < proven 145 MB)
    char* ws = (char*)d_ws;
    unsigned short* w3H = (unsigned short*)(ws + 0);          //  16384 B
    unsigned short* w3L = (unsigned short*)(ws + 16384);
    unsigned short* w4H = (unsigned short*)(ws + 32768);      //  65536 B
    unsigned short* w4L = (unsigned short*)(ws + 98304);
    unsigned short* w5H = (unsigned short*)(ws + 163840);     // 524288 B
    unsigned short* w5L = (unsigned short*)(ws + 688128);
    int*            idx = (int*)(ws + 1212416);               // 655360 B
    unsigned short* catH = (unsigned short*)(ws + 2097152);   // 33.55 MB
    unsigned short* catL = (unsigned short*)(ws + 35651584);  // 33.55 MB
    unsigned short* h3H  = (unsigned short*)(ws + 69206016);  // 41.94 MB
    float*          c2d  = (float*)(ws + 111149056);          // 131072 B
    // d_out doubles as scratch: h2 (hi|lo interleaved) then h3L in-place
    unsigned short* h2HL = (unsigned short*)d_out;
    unsigned short* h3L  = (unsigned short*)d_out;

    wsplit_kernel<<<dim3(1312), dim3(256), 0, stream>>>(w3, w4, w5, x,
                                                        w3H, w3L, w4H, w4L, w5H, w5L,
                                                        c2d);
    knn_kernel<<<dim3(BATCH * NPTS / 64), dim3(1024), 0, stream>>>(x, c2d, idx);
    mlp12_kernel<<<dim3(BATCH * NPTS / 16), dim3(256), 0, stream>>>(x, idx, w1, w2,
                                                                    h2HL, catH, catL);
    mlp3_kernel<<<dim3(BATCH * NPTS * KNN / 80), dim3(256), 0, stream>>>(
        h2HL, w3H, w3L, h3H, h3L, catH, catL);
    mlp4_kernel<<<dim3(BATCH * NPTS * KNN / 80, 2), dim3(256), 0, stream>>>(
        h3H, h3L, w4H, w4L, catH, catL);
    gemm512_kernel<<<dim3(BATCH * NPTS / 128, 4), dim3(256), 0, stream>>>(
        catH, catL, w5H, w5L, out);
}

// Round 10
// 408.064 us; speedup vs baseline: 1.1442x; 1.1442x over previous
//
#include <hip/hip_runtime.h>
#include <cstdint>

#define BATCH 4
#define NPTS  8192
#define KNN   5
#define CAPQ  176

typedef short bf16x8 __attribute__((ext_vector_type(8)));
typedef float f32x4  __attribute__((ext_vector_type(4)));
#define MFMA16(a, b, c) __builtin_amdgcn_mfma_f32_16x16x32_bf16((a), (b), (c), 0, 0, 0)

__device__ __forceinline__ unsigned short f2bf(float x) {
    unsigned u = __float_as_uint(x);
    unsigned r = u + 0x7fffu + ((u >> 16) & 1u);   // RN-even
    return (unsigned short)(r >> 16);
}
__device__ __forceinline__ float bf2f(unsigned short h) {
    return __uint_as_float(((unsigned)h) << 16);
}
// async global->LDS, 16B/lane; LDS dest = wave-uniform base + lane*16
__device__ __forceinline__ void gload16(const void* g, void* l) {
    __builtin_amdgcn_global_load_lds(
        (const __attribute__((address_space(1))) unsigned int*)g,
        (__attribute__((address_space(3))) unsigned int*)l, 16, 0, 0);
}

// ---------------------------------------------------------------------------
// Kernel W: split w3/w4/w5 into bf16 hi/lo pairs (fp32-emulation operands)
// + precompute |c|^2 for every point (c2, used by knn's dot-form distance).
// ---------------------------------------------------------------------------
__global__ __launch_bounds__(256) void wsplit_kernel(
        const float* __restrict__ w3, const float* __restrict__ w4,
        const float* __restrict__ w5, const float* __restrict__ x,
        unsigned short* __restrict__ w3H, unsigned short* __restrict__ w3L,
        unsigned short* __restrict__ w4H, unsigned short* __restrict__ w4L,
        unsigned short* __restrict__ w5H, unsigned short* __restrict__ w5L,
        float* __restrict__ c2) {
    const int i = blockIdx.x * 256 + threadIdx.x;   // 335872 total, exact grid
    if (i >= 303104) {                              // 32768 point-norm entries
        const int pt = i - 303104;
        const int b = pt >> 13, n = pt & 8191;
        const float* xb = x + (size_t)b * 3 * NPTS;
        const float cx = xb[n], cy = xb[NPTS + n], cz = xb[2 * NPTS + n];
        c2[pt] = fmaf(cz, cz, fmaf(cy, cy, cx * cx));
        return;
    }
    const float* src; unsigned short *dh, *dl; int off;
    if (i < 8192)       { src = w3; dh = w3H; dl = w3L; off = i; }
    else if (i < 40960) { src = w4; dh = w4H; dl = w4L; off = i - 8192; }
    else                { src = w5; dh = w5H; dl = w5L; off = i - 40960; }
    const float v = src[off];
    const unsigned short hi = f2bf(v);
    dh[off] = hi;
    dl[off] = f2bf(v - bf2f(hi));
}

// ---------------------------------------------------------------------------
// Kernel A: exact 5-NN, v10 (pair-min top-5 chain).
// d' = |c|^2 - 2 q.c (dot form). 16 waves/block, 32 waves/CU, LDS-staged
// candidates, uniform-address ds_read_b128 broadcast. Pass A inserts PAIR
// MINIMA (disjoint pairs): 5 smallest pair-mins are actual distances of 5
// distinct candidates -> slice-5th-of-pairmins >= global 5th (pigeonhole
// valid). 6 VALU/cand, branch-free. CAPQ=176 (accept bound 2*5*16=160 +
// margin extras). thrA aliases qidx (dead after threshold reduction).
// Pass C: 4 phases x 16 queries, exact fp64 re-rank. Margin 4e-4.
// ---------------------------------------------------------------------------
__global__ __launch_bounds__(1024, 8) void knn_kernel(const float* __restrict__ x,
                                                      const float* __restrict__ c2,
                                                      int* __restrict__ idx_out) {
    __shared__ __align__(16) char sbuf[32768];  // stage[16][128] f4 / qd union
    __shared__ __align__(16) char buf2[45056];  // qidx[64*176] (thrA aliases 4KB)
    __shared__ float  thrQ[64];         //  per-query threshold
    __shared__ int    qcnt[64];

    float* thrA = (float*)buf2;         // [16][64] slice 5th-of-pairmins
    int*   qidx = (int*)buf2;           // [64][CAPQ] finalist indices

    const int t = threadIdx.x;
    const int lane = t & 63;            // query lane
    const int s = t >> 6;               // slice 0..15 (wave-uniform)
    const int b = blockIdx.x >> 7;
    const int q0 = (blockIdx.x & 127) * 64;
    const int qg = q0 + lane;
    const float* xb = x + (size_t)b * 3 * NPTS;

    float4* stw = ((float4*)sbuf) + s * 128;   // wave-private 2KB stage
    double* qd  = (double*)sbuf;               // pass-C alias (stage dead then)

    const float nqx = -2.0f * xb[qg];
    const float nqy = -2.0f * xb[NPTS + qg];
    const float nqz = -2.0f * xb[2 * NPTS + qg];

    if (t < 64) qcnt[t] = 0;

    const float2* gx = (const float2*)xb;
    const float2* gy = (const float2*)(xb + NPTS);
    const float2* gz = (const float2*)(xb + 2 * NPTS);
    const float2* gc = (const float2*)(c2 + b * NPTS);
    const int f2base = s * 256;         // float2-group base of this slice

    // ---- Pass A: top-5 of pair minima (branch-free chain) ----
    float s0 = 3e38f, s1 = 3e38f, s2 = 3e38f, s3 = 3e38f, s4 = 3e38f;
    {
        float2 xv = gx[f2base + lane], yv = gy[f2base + lane];
        float2 zv = gz[f2base + lane], cv = gc[f2base + lane];
        for (int ch = 0; ch < 4; ++ch) {
            stw[0 * 64 + lane] = make_float4(xv.x, yv.x, zv.x, cv.x);
            stw[1 * 64 + lane] = make_float4(xv.y, yv.y, zv.y, cv.y);
            if (ch < 3) {               // prefetch next chunk under compute
                const int f2 = f2base + (ch + 1) * 64 + lane;
                xv = gx[f2]; yv = gy[f2]; zv = gz[f2]; cv = gc[f2];
            }
            for (int u4 = 0; u4 < 32; ++u4) {
                float4 cd[4];
                #pragma unroll
                for (int j = 0; j < 4; ++j) cd[j] = stw[u4 * 4 + j];
                float d[4];
                #pragma unroll
                for (int j = 0; j < 4; ++j)
                    d[j] = fmaf(cd[j].x, nqx,
                           fmaf(cd[j].y, nqy, fmaf(cd[j].z, nqz, cd[j].w)));
                const float m0 = fminf(d[0], d[1]);
                const float m1 = fminf(d[2], d[3]);
                s4 = __builtin_amdgcn_fmed3f(s3, m0, s4);
                s3 = __builtin_amdgcn_fmed3f(s2, m0, s3);
                s2 = __builtin_amdgcn_fmed3f(s1, m0, s2);
                s1 = __builtin_amdgcn_fmed3f(s0, m0, s1);
                s0 = fminf(s0, m0);
                s4 = __builtin_amdgcn_fmed3f(s3, m1, s4);
                s3 = __builtin_amdgcn_fmed3f(s2, m1, s3);
                s2 = __builtin_amdgcn_fmed3f(s1, m1, s2);
                s1 = __builtin_amdgcn_fmed3f(s0, m1, s1);
                s0 = fminf(s0, m1);
            }
        }
    }
    thrA[s * 64 + lane] = s4;
    __syncthreads();
    if (t < 64) {
        float m = thrA[t];
        #pragma unroll
        for (int ww = 1; ww < 16; ++ww) m = fminf(m, thrA[ww * 64 + t]);
        thrQ[t] = m + 4e-4f;            // margin > 2x worst-case fp32 error
    }
    __syncthreads();                    // thrA dead; qidx alias live below

    // ---- Pass B: compact accepted candidate indices per query ----
    const float thrq = thrQ[lane];
    {
        float2 xv = gx[f2base + lane], yv = gy[f2base + lane];
        float2 zv = gz[f2base + lane], cv = gc[f2base + lane];
        for (int ch = 0; ch < 4; ++ch) {
            const int cb = s * 512 + ch * 128;    // chunk candidate base
            stw[0 * 64 + lane] = make_float4(xv.x, yv.x, zv.x, cv.x);
            stw[1 * 64 + lane] = make_float4(xv.y, yv.y, zv.y, cv.y);
            if (ch < 3) {
                const int f2 = f2base + (ch + 1) * 64 + lane;
                xv = gx[f2]; yv = gy[f2]; zv = gz[f2]; cv = gc[f2];
            }
            for (int u4 = 0; u4 < 32; ++u4) {
                float4 cd[4];
                #pragma unroll
                for (int j = 0; j < 4; ++j) cd[j] = stw[u4 * 4 + j];
                float d[4];
                #pragma unroll
                for (int j = 0; j < 4; ++j)
                    d[j] = fmaf(cd[j].x, nqx,
                           fmaf(cd[j].y, nqy, fmaf(cd[j].z, nqz, cd[j].w)));
                const float dmin = fminf(fminf(d[0], d[1]), fminf(d[2], d[3]));
                if (dmin < thrq) {
                    #pragma unroll
                    for (int j = 0; j < 4; ++j) {
                        if (d[j] < thrq) {
                            const int slot = atomicAdd(&qcnt[lane], 1);
                            const int u = u4 * 4 + j;
                            const int gid = cb + 2 * (u & 63) + (u >> 6);
                            if (slot < CAPQ) qidx[lane * CAPQ + slot] = gid;
                        }
                    }
                }
            }
        }
    }

    // ---- Pass C: exact fp64 distances + lexicographic rank select ----
    // 4 phases of 16 queries (qd alias fits 32KB stage); 64 threads/query.
    const int qll = t >> 6;               // 0..15 (local query)
    const int jt = t & 63;
    for (int ph = 0; ph < 4; ++ph) {
        __syncthreads();                  // stage/qd region handoff
        const int ql = ph * 16 + qll;
        const int cnt = min(qcnt[ql], CAPQ);
        const double Qx = (double)xb[q0 + ql];
        const double Qy = (double)xb[NPTS + q0 + ql];
        const double Qz = (double)xb[2 * NPTS + q0 + ql];
        for (int j = jt; j < cnt; j += 64) {
            const int ci = qidx[ql * CAPQ + j];
            const double ddx = Qx - (double)xb[ci];
            const double ddy = Qy - (double)xb[NPTS + ci];
            const double ddz = Qz - (double)xb[2 * NPTS + ci];
            qd[qll * CAPQ + j] = ddx * ddx + ddy * ddy + ddz * ddz;
        }
        __syncthreads();
        for (int j = jt; j < cnt; j += 64) {
            const double dj = qd[qll * CAPQ + j];
            const int    ij = qidx[ql * CAPQ + j];
            int rank = 0;
            for (int k = 0; k < cnt; ++k) {
                const double dk = qd[qll * CAPQ + k];
                const int    ik = qidx[ql * CAPQ + k];
                rank += (dk < dj) || (dk == dj && ik < ij);
            }
            if (rank < KNN)
                idx_out[((size_t)b * NPTS + q0 + ql) * KNN + rank] = ij;
        }
    }
}

// ---------------------------------------------------------------------------
// Kernel B1: gather + L1 (6->64) + x1max + L2 (64->64) + x2max (fp32 compute).
// Epilogue writes h2 as interleaved bf16 hi|lo rows (d_out scratch) and
// x1/x2 into catH/catL.
// ---------------------------------------------------------------------------
__global__ __launch_bounds__(256) void mlp12_kernel(const float* __restrict__ x,
                                                    const int* __restrict__ idx,
                                                    const float* __restrict__ w1,
                                                    const float* __restrict__ w2,
                                                    unsigned short* __restrict__ h2HL,
                                                    unsigned short* __restrict__ catH,
                                                    unsigned short* __restrict__ catL) {
    __shared__ float w1s[64 * 6];
    __shared__ float w2s[64 * 68];
    __shared__ float fbuf[80][6];
    __shared__ float h1s[80 * 68];
    __shared__ float h2s[80 * 68];
    const int t = threadIdx.x;
    const int pbase = blockIdx.x * 16;

    for (int i = t; i < 384; i += 256) w1s[i] = w1[i];
    for (int i = t; i < 4096; i += 256) {
        int c = i >> 6, q = i & 63;
        w2s[c * 68 + q] = w2[i];
    }
    if (t < 80) {
        const int pt = pbase + t / 5;
        const int b = pt >> 13;
        const int n = pt & 8191;
        const int k = t % 5;
        const int j = idx[(size_t)pt * KNN + k];
        const float* xb = x + (size_t)b * 3 * NPTS;
        fbuf[t][0] = xb[j];
        fbuf[t][1] = xb[NPTS + j];
        fbuf[t][2] = xb[2 * NPTS + j];
        fbuf[t][3] = xb[n];
        fbuf[t][4] = xb[NPTS + n];
        fbuf[t][5] = xb[2 * NPTS + n];
    }
    __syncthreads();

    for (int o = t; o < 5120; o += 256) {
        const int r = o >> 6, c = o & 63;
        float acc = 0.f;
        #pragma unroll
        for (int q = 0; q < 6; ++q) acc = fmaf(w1s[c * 6 + q], fbuf[r][q], acc);
        h1s[r * 68 + c] = fmaxf(acc, 0.f);
    }
    __syncthreads();

    for (int o = t; o < 1024; o += 256) {
        const int p = o >> 6, c = o & 63;
        float m = h1s[(p * 5) * 68 + c];
        #pragma unroll
        for (int k = 1; k < 5; ++k) m = fmaxf(m, h1s[(p * 5 + k) * 68 + c]);
        const unsigned short hi = f2bf(m);
        const size_t co = (size_t)(pbase + p) * 512 + c;
        catH[co] = hi;
        catL[co] = f2bf(m - bf2f(hi));
    }

    for (int tile = t; tile < 320; tile += 256) {
        const int r0 = (tile % 20) * 4;
        const int c0 = (tile / 20) * 4;
        float acc[4][4] = {};
        for (int q = 0; q < 64; q += 4) {
            float4 a[4], w[4];
            #pragma unroll
            for (int i = 0; i < 4; ++i) a[i] = *(const float4*)&h1s[(r0 + i) * 68 + q];
            #pragma unroll
            for (int j = 0; j < 4; ++j) w[j] = *(const float4*)&w2s[(c0 + j) * 68 + q];
            #pragma unroll
            for (int i = 0; i < 4; ++i)
                #pragma unroll
                for (int j = 0; j < 4; ++j) {
                    acc[i][j] = fmaf(a[i].x, w[j].x, acc[i][j]);
                    acc[i][j] = fmaf(a[i].y, w[j].y, acc[i][j]);
                    acc[i][j] = fmaf(a[i].z, w[j].z, acc[i][j]);
                    acc[i][j] = fmaf(a[i].w, w[j].w, acc[i][j]);
                }
        }
        #pragma unroll
        for (int i = 0; i < 4; ++i)
            #pragma unroll
            for (int j = 0; j < 4; ++j)
                h2s[(r0 + i) * 68 + c0 + j] = fmaxf(acc[i][j], 0.f);
    }
    __syncthreads();

    for (int o = t; o < 1024; o += 256) {
        const int p = o >> 6, c = o & 63;
        float m = h2s[(p * 5) * 68 + c];
        #pragma unroll
        for (int k = 1; k < 5; ++k) m = fmaxf(m, h2s[(p * 5 + k) * 68 + c]);
        const unsigned short hi = f2bf(m);
        const size_t co = (size_t)(pbase + p) * 512 + 64 + c;
        catH[co] = hi;
        catL[co] = f2bf(m - bf2f(hi));
    }
    for (int o = t; o < 5120; o += 256) {
        const int r = o >> 6, c = o & 63;
        const float v = h2s[r * 68 + c];
        const unsigned short hi = f2bf(v);
        const size_t rowb = (size_t)(pbase * 5 + r) * 128;
        h2HL[rowb + c]      = hi;
        h2HL[rowb + 64 + c] = f2bf(v - bf2f(hi));
    }
}

// ---------------------------------------------------------------------------
// Kernel B2: L3 (64->128) via split-bf16 MFMA + x3max.
// ---------------------------------------------------------------------------
__global__ __launch_bounds__(256) void mlp3_kernel(
        const unsigned short* __restrict__ h2HL,
        const unsigned short* __restrict__ w3H, const unsigned short* __restrict__ w3L,
        unsigned short* __restrict__ h3H, unsigned short* __restrict__ h3L,
        unsigned short* __restrict__ catH, unsigned short* __restrict__ catL) {
    __shared__ __align__(16) char smem[59904];
    unsigned short* aH = (unsigned short*)smem;            // [80][72]
    unsigned short* aL = aH + 80 * 72;                     // @11520B
    unsigned short* bH = (unsigned short*)(smem + 23040);  // [128][72]
    unsigned short* bL = (unsigned short*)(smem + 41472);

    const int t = threadIdx.x;
    const int R0 = blockIdx.x * 80;
    const int P0 = blockIdx.x * 16;

    for (int c = t; c < 1280; c += 256) {                  // A: h2 hi|lo rows
        const int row = c >> 4, seg = c & 15;
        const uint4 v = *(const uint4*)(h2HL + (size_t)(R0 + row) * 128 + seg * 8);
        *(uint4*)((seg < 8 ? aH : aL) + row * 72 + (seg & 7) * 8) = v;
    }
    for (int c = t; c < 1024; c += 256) {                  // B hi
        const int row = c >> 3, seg = c & 7;
        *(uint4*)(bH + row * 72 + seg * 8) =
            *(const uint4*)(w3H + row * 64 + seg * 8);
    }
    for (int c = t; c < 1024; c += 256) {                  // B lo
        const int row = c >> 3, seg = c & 7;
        *(uint4*)(bL + row * 72 + seg * 8) =
            *(const uint4*)(w3L + row * 64 + seg * 8);
    }
    __syncthreads();

    const int w = t >> 6, lane = t & 63;
    const int q = lane >> 4, l16 = lane & 15;
    const int n0 = w * 32;

    f32x4 acc[5][2];
    #pragma unroll
    for (int mt = 0; mt < 5; ++mt)
        #pragma unroll
        for (int nt = 0; nt < 2; ++nt)
            acc[mt][nt] = (f32x4){0.f, 0.f, 0.f, 0.f};

    #pragma unroll
    for (int kt = 0; kt < 2; ++kt) {
        const int k0 = kt * 32 + q * 8;
        bf16x8 bh[2], bl[2];
        #pragma unroll
        for (int nt = 0; nt < 2; ++nt) {
            bh[nt] = *(const bf16x8*)(bH + (n0 + nt * 16 + l16) * 72 + k0);
            bl[nt] = *(const bf16x8*)(bL + (n0 + nt * 16 + l16) * 72 + k0);
        }
        #pragma unroll
        for (int mt = 0; mt < 5; ++mt) {
            const bf16x8 ah = *(const bf16x8*)(aH + (mt * 16 + l16) * 72 + k0);
            const bf16x8 al = *(const bf16x8*)(aL + (mt * 16 + l16) * 72 + k0);
            #pragma unroll
            for (int nt = 0; nt < 2; ++nt) {
                acc[mt][nt] = MFMA16(ah, bh[nt], acc[mt][nt]);
                acc[mt][nt] = MFMA16(ah, bl[nt], acc[mt][nt]);
                acc[mt][nt] = MFMA16(al, bh[nt], acc[mt][nt]);
            }
        }
    }

    __syncthreads();                       // A/B staging dead; alias Dbuf
    float* Dbuf = (float*)smem;            // [80][132] fp32
    #pragma unroll
    for (int mt = 0; mt < 5; ++mt)
        #pragma unroll
        for (int nt = 0; nt < 2; ++nt)
            #pragma unroll
            for (int r = 0; r < 4; ++r)
                Dbuf[(mt * 16 + q * 4 + r) * 132 + n0 + nt * 16 + l16] =
                    fmaxf(acc[mt][nt][r], 0.f);
    __syncthreads();

    {
        const int col = t & 127;
        const int p0 = (t >> 7) * 8;
        #pragma unroll
        for (int p = 0; p < 8; ++p) {
            const int pp = p0 + p;
            float mx = 0.f;
            #pragma unroll
            for (int k = 0; k < 5; ++k) {
                const int row = pp * 5 + k;
                const float v = Dbuf[row * 132 + col];
                const unsigned short hi = f2bf(v);
                const unsigned short lo = f2bf(v - bf2f(hi));
                const size_t off = (size_t)(R0 + row) * 128 + col;
                h3H[off] = hi;
                h3L[off] = lo;
                mx = fmaxf(mx, bf2f(hi) + bf2f(lo));
            }
            const unsigned short mh = f2bf(mx);
            const size_t co = (size_t)(P0 + pp) * 512 + 128 + col;
            catH[co] = mh;
            catL[co] = f2bf(mx - bf2f(mh));
        }
    }
}

// ---------------------------------------------------------------------------
// Kernel C: L4 (128->256) via split-bf16 MFMA + x4max.
// ---------------------------------------------------------------------------
__global__ __launch_bounds__(256) void mlp4_kernel(
        const unsigned short* __restrict__ h3H, const unsigned short* __restrict__ h3L,
        const unsigned short* __restrict__ w4H, const unsigned short* __restrict__ w4L,
        unsigned short* __restrict__ catH, unsigned short* __restrict__ catL) {
    __shared__ __align__(16) char smem[64000];
    unsigned short* aH = (unsigned short*)smem;            // [80][136]
    unsigned short* aL = aH + 80 * 136;                    // @21760B
    unsigned short* bH = (unsigned short*)(smem + 43520);  // [128][40] per k-step
    unsigned short* bL = (unsigned short*)(smem + 53760);

    const int t = threadIdx.x;
    const int R0 = blockIdx.x * 80;
    const int P0 = blockIdx.x * 16;
    const int ny = blockIdx.y;                             // cout half

    for (int c = t; c < 1280; c += 256) {                  // A hi
        const int row = c >> 4, seg = c & 15;
        *(uint4*)(aH + row * 136 + seg * 8) =
            *(const uint4*)(h3H + (size_t)(R0 + row) * 128 + seg * 8);
    }
    for (int c = t; c < 1280; c += 256) {                  // A lo
        const int row = c >> 4, seg = c & 15;
        *(uint4*)(aL + row * 136 + seg * 8) =
            *(const uint4*)(h3L + (size_t)(R0 + row) * 128 + seg * 8);
    }

    const int w = t >> 6, lane = t & 63;
    const int q = lane >> 4, l16 = lane & 15;
    const int n0 = w * 32;

    f32x4 acc[5][2];
    #pragma unroll
    for (int mt = 0; mt < 5; ++mt)
        #pragma unroll
        for (int nt = 0; nt < 2; ++nt)
            acc[mt][nt] = (f32x4){0.f, 0.f, 0.f, 0.f};

    for (int ks = 0; ks < 4; ++ks) {
        __syncthreads();
        #pragma unroll
        for (int i = 0; i < 2; ++i) {                      // B hi: 512 chunks
            const int c = t + i * 256;
            const int row = c >> 2, seg = c & 3;
            *(uint4*)(bH + row * 40 + seg * 8) =
                *(const uint4*)(w4H + (size_t)(ny * 128 + row) * 128 + ks * 32 + seg * 8);
        }
        #pragma unroll
        for (int i = 0; i < 2; ++i) {                      // B lo
            const int c = t + i * 256;
            const int row = c >> 2, seg = c & 3;
            *(uint4*)(bL + row * 40 + seg * 8) =
                *(const uint4*)(w4L + (size_t)(ny * 128 + row) * 128 + ks * 32 + seg * 8);
        }
        __syncthreads();

        const int k0 = ks * 32 + q * 8;
        const int kb = q * 8;
        bf16x8 bh[2], bl[2];
        #pragma unroll
        for (int nt = 0; nt < 2; ++nt) {
            bh[nt] = *(const bf16x8*)(bH + (n0 + nt * 16 + l16) * 40 + kb);
            bl[nt] = *(const bf16x8*)(bL + (n0 + nt * 16 + l16) * 40 + kb);
        }
        #pragma unroll
        for (int mt = 0; mt < 5; ++mt) {
            const bf16x8 ah = *(const bf16x8*)(aH + (mt * 16 + l16) * 136 + k0);
            const bf16x8 al = *(const bf16x8*)(aL + (mt * 16 + l16) * 136 + k0);
            #pragma unroll
            for (int nt = 0; nt < 2; ++nt) {
                acc[mt][nt] = MFMA16(ah, bh[nt], acc[mt][nt]);
                acc[mt][nt] = MFMA16(ah, bl[nt], acc[mt][nt]);
                acc[mt][nt] = MFMA16(al, bh[nt], acc[mt][nt]);
            }
        }
    }

    __syncthreads();
    float* Dbuf = (float*)smem;            // [80][132] fp32
    #pragma unroll
    for (int mt = 0; mt < 5; ++mt)
        #pragma unroll
        for (int nt = 0; nt < 2; ++nt)
            #pragma unroll
            for (int r = 0; r < 4; ++r)
                Dbuf[(mt * 16 + q * 4 + r) * 132 + n0 + nt * 16 + l16] =
                    fmaxf(acc[mt][nt][r], 0.f);
    __syncthreads();

    {
        const int col = t & 127;
        const int p0 = (t >> 7) * 8;
        const int cout = 256 + ny * 128 + col;
        #pragma unroll
        for (int p = 0; p < 8; ++p) {
            const int pp = p0 + p;
            float mx = 0.f;
            #pragma unroll
            for (int k = 0; k < 5; ++k)
                mx = fmaxf(mx, Dbuf[(pp * 5 + k) * 132 + col]);
            const unsigned short mh = f2bf(mx);
            const size_t co = (size_t)(P0 + pp) * 512 + cout;
            catH[co] = mh;
            catL[co] = f2bf(mx - bf2f(mh));
        }
    }
}

// ---------------------------------------------------------------------------
// Kernel D: final GEMM out = relu(cat(32768x512) * W5^T), split-bf16 MFMA.
// v3: staging via global_load_lds width=16, full-tile coverage (fixes v2's
// half-tile bug: one gload16/wave = 16 rows; tile needs 128 rows -> each
// wave stages 32 rows in TWO 16-row halves, 2 gload16 per array).
// Linear unpadded [128][32]-short tiles (64B rows); wave w region =
// w*1024 shorts (2KB), halves at +0/+512. LDS dest wave-uniform + lane*16;
// global source per-lane (row = 32w + lane>>2 [+16], seg = lane&3).
// ---------------------------------------------------------------------------
__global__ __launch_bounds__(256) void gemm512_kernel(
        const unsigned short* __restrict__ catH, const unsigned short* __restrict__ catL,
        const unsigned short* __restrict__ w5H, const unsigned short* __restrict__ w5L,
        float* __restrict__ out) {
    __shared__ __align__(16) char smem[32768];
    unsigned short* aH = (unsigned short*)smem;            // [128][32] @0 (8KB)
    unsigned short* aL = aH + 128 * 32;                    // @8192
    unsigned short* bH = (unsigned short*)(smem + 16384);  // [128][32]
    unsigned short* bL = (unsigned short*)(smem + 24576);

    const int t = threadIdx.x;
    const int m0 = blockIdx.x * 128;
    const int n0blk = blockIdx.y * 128;

    const int w = t >> 6, lane = t & 63;
    const int q = lane >> 4, l16 = lane & 15;
    const int m_off = (w >> 1) * 64;
    const int n_off = (w & 1) * 64;

    // staging: wave w stages rows 32w..32w+31 (2KB/tile) in two halves.
    const int srow = w * 32 + (lane >> 2);   // first-half row
    const int sseg = lane & 3;
    const size_t ar0 = (size_t)(m0 + srow) * 512 + sseg * 8;
    const size_t ar1 = ar0 + 16 * 512;       // row + 16
    const size_t br0 = (size_t)(n0blk + srow) * 512 + sseg * 8;
    const size_t br1 = br0 + 16 * 512;
    const int ld0 = w * 1024;                // shorts; +512 = second half

    f32x4 acc[4][4];
    #pragma unroll
    for (int mt = 0; mt < 4; ++mt)
        #pragma unroll
        for (int nt = 0; nt < 4; ++nt)
            acc[mt][nt] = (f32x4){0.f, 0.f, 0.f, 0.f};

    for (int kc = 0; kc < 512; kc += 32) {
        __syncthreads();                 // WAR: previous chunk's reads done
        gload16(catH + ar0 + kc, aH + ld0);
        gload16(catH + ar1 + kc, aH + ld0 + 512);
        gload16(catL + ar0 + kc, aL + ld0);
        gload16(catL + ar1 + kc, aL + ld0 + 512);
        gload16(w5H + br0 + kc, bH + ld0);
        gload16(w5H + br1 + kc, bH + ld0 + 512);
        gload16(w5L + br0 + kc, bL + ld0);
        gload16(w5L + br1 + kc, bL + ld0 + 512);
        __syncthreads();                 // drains vmcnt -> staged data visible

        const int k0 = q * 8;
        bf16x8 bh[4], bl[4];
        #pragma unroll
        for (int nt = 0; nt < 4; ++nt) {
            bh[nt] = *(const bf16x8*)(bH + (n_off + nt * 16 + l16) * 32 + k0);
            bl[nt] = *(const bf16x8*)(bL + (n_off + nt * 16 + l16) * 32 + k0);
        }
        #pragma unroll
        for (int mt = 0; mt < 4; ++mt) {
            const bf16x8 ah = *(const bf16x8*)(aH + (m_off + mt * 16 + l16) * 32 + k0);
            const bf16x8 al = *(const bf16x8*)(aL + (m_off + mt * 16 + l16) * 32 + k0);
            #pragma unroll
            for (int nt = 0; nt < 4; ++nt) {
                acc[mt][nt] = MFMA16(ah, bh[nt], acc[mt][nt]);
                acc[mt][nt] = MFMA16(ah, bl[nt], acc[mt][nt]);
                acc[mt][nt] = MFMA16(al, bh[nt], acc[mt][nt]);
            }
        }
    }

    // band-wise epilogue: 8 bands of 16 rows; LDS transpose for coalesced out
    float* bandbuf = (float*)smem;         // [16][132] fp32 (8448B <= 32KB)
    for (int b8 = 0; b8 < 8; ++b8) {
        __syncthreads();
        if ((w >> 1) == (b8 >> 2)) {
            const int mt = b8 & 3;
            #pragma unroll
            for (int nt = 0; nt < 4; ++nt)
                #pragma unroll
                for (int r = 0; r < 4; ++r)
                    bandbuf[(q * 4 + r) * 132 + n_off + nt * 16 + l16] =
                        fmaxf(acc[mt][nt][r], 0.f);
        }
        __syncthreads();
        const int col = t >> 1;
        const int ph = (t & 1) * 8;
        const int P = m0 + b8 * 16 + ph;
        const int bb = P >> 13, nn = P & 8191;
        const int cout = n0blk + col;
        float tmp[8];
        #pragma unroll
        for (int j = 0; j < 8; ++j) tmp[j] = bandbuf[(ph + j) * 132 + col];
        float* op = &out[((size_t)bb * 512 + cout) * NPTS + nn];
        *(float4*)op       = make_float4(tmp[0], tmp[1], tmp[2], tmp[3]);
        *(float4*)(op + 4) = make_float4(tmp[4], tmp[5], tmp[6], tmp[7]);
    }
}

extern "C" void kernel_launch(void* const* d_in, const int* in_sizes, int n_in,
                              void* d_out, int out_size, void* d_ws, size_t ws_size,
                              hipStream_t stream) {
    (void)in_sizes; (void)n_in; (void)out_size; (void)ws_size;
    const float* x  = (const float*)d_in[0];
    const float* w1 = (const float*)d_in[1];
    const float* w2 = (const float*)d_in[2];
    const float* w3 = (const float*)d_in[3];
    const float* w4 = (const float*)d_in[4];
    const float* w5 = (const float*)d_in[5];
    float* out = (float*)d_out;

    // workspace layout (111.3 MB total, < proven 145 MB)
    char* ws = (char*)d_ws;
    unsigned short* w3H = (unsigned short*)(ws + 0);          //  16384 B
    unsigned short* w3L = (unsigned short*)(ws + 16384);
    unsigned short* w4H = (unsigned short*)(ws + 32768);      //  65536 B
    unsigned short* w4L = (unsigned short*)(ws + 98304);
    unsigned short* w5H = (unsigned short*)(ws + 163840);     // 524288 B
    unsigned short* w5L = (unsigned short*)(ws + 688128);
    int*            idx = (int*)(ws + 1212416);               // 655360 B
    unsigned short* catH = (unsigned short*)(ws + 2097152);   // 33.55 MB
    unsigned short* catL = (unsigned short*)(ws + 35651584);  // 33.55 MB
    unsigned short* h3H  = (unsigned short*)(ws + 69206016);  // 41.94 MB
    float*          c2d  = (float*)(ws + 111149056);          // 131072 B
    // d_out doubles as scratch: h2 (hi|lo interleaved) then h3L in-place
    unsigned short* h2HL = (unsigned short*)d_out;
    unsigned short* h3L  = (unsigned short*)d_out;

    wsplit_kernel<<<dim3(1312), dim3(256), 0, stream>>>(w3, w4, w5, x,
                                                        w3H, w3L, w4H, w4L, w5H, w5L,
                                                        c2d);
    knn_kernel<<<dim3(BATCH * NPTS / 64), dim3(1024), 0, stream>>>(x, c2d, idx);
    mlp12_kernel<<<dim3(BATCH * NPTS / 16), dim3(256), 0, stream>>>(x, idx, w1, w2,
                                                                    h2HL, catH, catL);
    mlp3_kernel<<<dim3(BATCH * NPTS * KNN / 80), dim3(256), 0, stream>>>(
        h2HL, w3H, w3L, h3H, h3L, catH, catL);
    mlp4_kernel<<<dim3(BATCH * NPTS * KNN / 80, 2), dim3(256), 0, stream>>>(
        h3H, h3L, w4H, w4L, catH, catL);
    gemm512_kernel<<<dim3(BATCH * NPTS / 128, 4), dim3(256), 0, stream>>>(
        catH, catL, w5H, w5L, out);
}

// Round 11
// 366.341 us; speedup vs baseline: 1.2745x; 1.1139x over previous
//
#include <hip/hip_runtime.h>
#include <cstdint>

#define BATCH 4
#define NPTS  8192
#define KNN   5
#define CAPQ  176

typedef short bf16x8 __attribute__((ext_vector_type(8)));
typedef float f32x4  __attribute__((ext_vector_type(4)));
#define MFMA16(a, b, c) __builtin_amdgcn_mfma_f32_16x16x32_bf16((a), (b), (c), 0, 0, 0)

__device__ __forceinline__ unsigned short f2bf(float x) {
    unsigned u = __float_as_uint(x);
    unsigned r = u + 0x7fffu + ((u >> 16) & 1u);   // RN-even
    return (unsigned short)(r >> 16);
}
__device__ __forceinline__ float bf2f(unsigned short h) {
    return __uint_as_float(((unsigned)h) << 16);
}
// async global->LDS, 16B/lane; LDS dest = wave-uniform base + lane*16
__device__ __forceinline__ void gload16(const void* g, void* l) {
    __builtin_amdgcn_global_load_lds(
        (const __attribute__((address_space(1))) unsigned int*)g,
        (__attribute__((address_space(3))) unsigned int*)l, 16, 0, 0);
}

// ---------------------------------------------------------------------------
// Kernel W: split w3/w4/w5 into bf16 hi/lo pairs (fp32-emulation operands)
// + precompute |c|^2 for every point (c2, used by knn's dot-form distance).
// ---------------------------------------------------------------------------
__global__ __launch_bounds__(256) void wsplit_kernel(
        const float* __restrict__ w3, const float* __restrict__ w4,
        const float* __restrict__ w5, const float* __restrict__ x,
        unsigned short* __restrict__ w3H, unsigned short* __restrict__ w3L,
        unsigned short* __restrict__ w4H, unsigned short* __restrict__ w4L,
        unsigned short* __restrict__ w5H, unsigned short* __restrict__ w5L,
        float* __restrict__ c2) {
    const int i = blockIdx.x * 256 + threadIdx.x;   // 335872 total, exact grid
    if (i >= 303104) {                              // 32768 point-norm entries
        const int pt = i - 303104;
        const int b = pt >> 13, n = pt & 8191;
        const float* xb = x + (size_t)b * 3 * NPTS;
        const float cx = xb[n], cy = xb[NPTS + n], cz = xb[2 * NPTS + n];
        c2[pt] = fmaf(cz, cz, fmaf(cy, cy, cx * cx));
        return;
    }
    const float* src; unsigned short *dh, *dl; int off;
    if (i < 8192)       { src = w3; dh = w3H; dl = w3L; off = i; }
    else if (i < 40960) { src = w4; dh = w4H; dl = w4L; off = i - 8192; }
    else                { src = w5; dh = w5H; dl = w5L; off = i - 40960; }
    const float v = src[off];
    const unsigned short hi = f2bf(v);
    dh[off] = hi;
    dl[off] = f2bf(v - bf2f(hi));
}

// ---------------------------------------------------------------------------
// Kernel A: exact 5-NN, v10 (pair-min top-5 chain).
// d' = |c|^2 - 2 q.c (dot form). 16 waves/block, 32 waves/CU, LDS-staged
// candidates, uniform-address ds_read_b128 broadcast. Pass A inserts PAIR
// MINIMA (disjoint pairs): 5 smallest pair-mins are actual distances of 5
// distinct candidates -> slice-5th-of-pairmins >= global 5th (pigeonhole
// valid). 6 VALU/cand, branch-free. CAPQ=176 (accept bound 2*5*16=160 +
// margin extras). thrA aliases qidx (dead after threshold reduction).
// Pass C: 4 phases x 16 queries, exact fp64 re-rank. Margin 4e-4.
// ---------------------------------------------------------------------------
__global__ __launch_bounds__(1024, 8) void knn_kernel(const float* __restrict__ x,
                                                      const float* __restrict__ c2,
                                                      int* __restrict__ idx_out) {
    __shared__ __align__(16) char sbuf[32768];  // stage[16][128] f4 / qd union
    __shared__ __align__(16) char buf2[45056];  // qidx[64*176] (thrA aliases 4KB)
    __shared__ float  thrQ[64];         //  per-query threshold
    __shared__ int    qcnt[64];

    float* thrA = (float*)buf2;         // [16][64] slice 5th-of-pairmins
    int*   qidx = (int*)buf2;           // [64][CAPQ] finalist indices

    const int t = threadIdx.x;
    const int lane = t & 63;            // query lane
    const int s = t >> 6;               // slice 0..15 (wave-uniform)
    const int b = blockIdx.x >> 7;
    const int q0 = (blockIdx.x & 127) * 64;
    const int qg = q0 + lane;
    const float* xb = x + (size_t)b * 3 * NPTS;

    float4* stw = ((float4*)sbuf) + s * 128;   // wave-private 2KB stage
    double* qd  = (double*)sbuf;               // pass-C alias (stage dead then)

    const float nqx = -2.0f * xb[qg];
    const float nqy = -2.0f * xb[NPTS + qg];
    const float nqz = -2.0f * xb[2 * NPTS + qg];

    if (t < 64) qcnt[t] = 0;

    const float2* gx = (const float2*)xb;
    const float2* gy = (const float2*)(xb + NPTS);
    const float2* gz = (const float2*)(xb + 2 * NPTS);
    const float2* gc = (const float2*)(c2 + b * NPTS);
    const int f2base = s * 256;         // float2-group base of this slice

    // ---- Pass A: top-5 of pair minima (branch-free chain) ----
    float s0 = 3e38f, s1 = 3e38f, s2 = 3e38f, s3 = 3e38f, s4 = 3e38f;
    {
        float2 xv = gx[f2base + lane], yv = gy[f2base + lane];
        float2 zv = gz[f2base + lane], cv = gc[f2base + lane];
        for (int ch = 0; ch < 4; ++ch) {
            stw[0 * 64 + lane] = make_float4(xv.x, yv.x, zv.x, cv.x);
            stw[1 * 64 + lane] = make_float4(xv.y, yv.y, zv.y, cv.y);
            if (ch < 3) {               // prefetch next chunk under compute
                const int f2 = f2base + (ch + 1) * 64 + lane;
                xv = gx[f2]; yv = gy[f2]; zv = gz[f2]; cv = gc[f2];
            }
            for (int u4 = 0; u4 < 32; ++u4) {
                float4 cd[4];
                #pragma unroll
                for (int j = 0; j < 4; ++j) cd[j] = stw[u4 * 4 + j];
                float d[4];
                #pragma unroll
                for (int j = 0; j < 4; ++j)
                    d[j] = fmaf(cd[j].x, nqx,
                           fmaf(cd[j].y, nqy, fmaf(cd[j].z, nqz, cd[j].w)));
                const float m0 = fminf(d[0], d[1]);
                const float m1 = fminf(d[2], d[3]);
                s4 = __builtin_amdgcn_fmed3f(s3, m0, s4);
                s3 = __builtin_amdgcn_fmed3f(s2, m0, s3);
                s2 = __builtin_amdgcn_fmed3f(s1, m0, s2);
                s1 = __builtin_amdgcn_fmed3f(s0, m0, s1);
                s0 = fminf(s0, m0);
                s4 = __builtin_amdgcn_fmed3f(s3, m1, s4);
                s3 = __builtin_amdgcn_fmed3f(s2, m1, s3);
                s2 = __builtin_amdgcn_fmed3f(s1, m1, s2);
                s1 = __builtin_amdgcn_fmed3f(s0, m1, s1);
                s0 = fminf(s0, m1);
            }
        }
    }
    thrA[s * 64 + lane] = s4;
    __syncthreads();
    if (t < 64) {
        float m = thrA[t];
        #pragma unroll
        for (int ww = 1; ww < 16; ++ww) m = fminf(m, thrA[ww * 64 + t]);
        thrQ[t] = m + 4e-4f;            // margin > 2x worst-case fp32 error
    }
    __syncthreads();                    // thrA dead; qidx alias live below

    // ---- Pass B: compact accepted candidate indices per query ----
    const float thrq = thrQ[lane];
    {
        float2 xv = gx[f2base + lane], yv = gy[f2base + lane];
        float2 zv = gz[f2base + lane], cv = gc[f2base + lane];
        for (int ch = 0; ch < 4; ++ch) {
            const int cb = s * 512 + ch * 128;    // chunk candidate base
            stw[0 * 64 + lane] = make_float4(xv.x, yv.x, zv.x, cv.x);
            stw[1 * 64 + lane] = make_float4(xv.y, yv.y, zv.y, cv.y);
            if (ch < 3) {
                const int f2 = f2base + (ch + 1) * 64 + lane;
                xv = gx[f2]; yv = gy[f2]; zv = gz[f2]; cv = gc[f2];
            }
            for (int u4 = 0; u4 < 32; ++u4) {
                float4 cd[4];
                #pragma unroll
                for (int j = 0; j < 4; ++j) cd[j] = stw[u4 * 4 + j];
                float d[4];
                #pragma unroll
                for (int j = 0; j < 4; ++j)
                    d[j] = fmaf(cd[j].x, nqx,
                           fmaf(cd[j].y, nqy, fmaf(cd[j].z, nqz, cd[j].w)));
                const float dmin = fminf(fminf(d[0], d[1]), fminf(d[2], d[3]));
                if (dmin < thrq) {
                    #pragma unroll
                    for (int j = 0; j < 4; ++j) {
                        if (d[j] < thrq) {
                            const int slot = atomicAdd(&qcnt[lane], 1);
                            const int u = u4 * 4 + j;
                            const int gid = cb + 2 * (u & 63) + (u >> 6);
                            if (slot < CAPQ) qidx[lane * CAPQ + slot] = gid;
                        }
                    }
                }
            }
        }
    }

    // ---- Pass C: exact fp64 distances + lexicographic rank select ----
    // 4 phases of 16 queries (qd alias fits 32KB stage); 64 threads/query.
    const int qll = t >> 6;               // 0..15 (local query)
    const int jt = t & 63;
    for (int ph = 0; ph < 4; ++ph) {
        __syncthreads();                  // stage/qd region handoff
        const int ql = ph * 16 + qll;
        const int cnt = min(qcnt[ql], CAPQ);
        const double Qx = (double)xb[q0 + ql];
        const double Qy = (double)xb[NPTS + q0 + ql];
        const double Qz = (double)xb[2 * NPTS + q0 + ql];
        for (int j = jt; j < cnt; j += 64) {
            const int ci = qidx[ql * CAPQ + j];
            const double ddx = Qx - (double)xb[ci];
            const double ddy = Qy - (double)xb[NPTS + ci];
            const double ddz = Qz - (double)xb[2 * NPTS + ci];
            qd[qll * CAPQ + j] = ddx * ddx + ddy * ddy + ddz * ddz;
        }
        __syncthreads();
        for (int j = jt; j < cnt; j += 64) {
            const double dj = qd[qll * CAPQ + j];
            const int    ij = qidx[ql * CAPQ + j];
            int rank = 0;
            for (int k = 0; k < cnt; ++k) {
                const double dk = qd[qll * CAPQ + k];
                const int    ik = qidx[ql * CAPQ + k];
                rank += (dk < dj) || (dk == dj && ik < ij);
            }
            if (rank < KNN)
                idx_out[((size_t)b * NPTS + q0 + ql) * KNN + rank] = ij;
        }
    }
}

// ---------------------------------------------------------------------------
// Kernel B1: gather + L1 (6->64) + x1max + L2 (64->64) + x2max (fp32 compute).
// Epilogue writes h2 as interleaved bf16 hi|lo rows (d_out scratch) and
// x1/x2 into catH/catL.
// ---------------------------------------------------------------------------
__global__ __launch_bounds__(256) void mlp12_kernel(const float* __restrict__ x,
                                                    const int* __restrict__ idx,
                                                    const float* __restrict__ w1,
                                                    const float* __restrict__ w2,
                                                    unsigned short* __restrict__ h2HL,
                                                    unsigned short* __restrict__ catH,
                                                    unsigned short* __restrict__ catL) {
    __shared__ float w1s[64 * 6];
    __shared__ float w2s[64 * 68];
    __shared__ float fbuf[80][6];
    __shared__ float h1s[80 * 68];
    __shared__ float h2s[80 * 68];
    const int t = threadIdx.x;
    const int pbase = blockIdx.x * 16;

    for (int i = t; i < 384; i += 256) w1s[i] = w1[i];
    for (int i = t; i < 4096; i += 256) {
        int c = i >> 6, q = i & 63;
        w2s[c * 68 + q] = w2[i];
    }
    if (t < 80) {
        const int pt = pbase + t / 5;
        const int b = pt >> 13;
        const int n = pt & 8191;
        const int k = t % 5;
        const int j = idx[(size_t)pt * KNN + k];
        const float* xb = x + (size_t)b * 3 * NPTS;
        fbuf[t][0] = xb[j];
        fbuf[t][1] = xb[NPTS + j];
        fbuf[t][2] = xb[2 * NPTS + j];
        fbuf[t][3] = xb[n];
        fbuf[t][4] = xb[NPTS + n];
        fbuf[t][5] = xb[2 * NPTS + n];
    }
    __syncthreads();

    for (int o = t; o < 5120; o += 256) {
        const int r = o >> 6, c = o & 63;
        float acc = 0.f;
        #pragma unroll
        for (int q = 0; q < 6; ++q) acc = fmaf(w1s[c * 6 + q], fbuf[r][q], acc);
        h1s[r * 68 + c] = fmaxf(acc, 0.f);
    }
    __syncthreads();

    for (int o = t; o < 1024; o += 256) {
        const int p = o >> 6, c = o & 63;
        float m = h1s[(p * 5) * 68 + c];
        #pragma unroll
        for (int k = 1; k < 5; ++k) m = fmaxf(m, h1s[(p * 5 + k) * 68 + c]);
        const unsigned short hi = f2bf(m);
        const size_t co = (size_t)(pbase + p) * 512 + c;
        catH[co] = hi;
        catL[co] = f2bf(m - bf2f(hi));
    }

    for (int tile = t; tile < 320; tile += 256) {
        const int r0 = (tile % 20) * 4;
        const int c0 = (tile / 20) * 4;
        float acc[4][4] = {};
        for (int q = 0; q < 64; q += 4) {
            float4 a[4], w[4];
            #pragma unroll
            for (int i = 0; i < 4; ++i) a[i] = *(const float4*)&h1s[(r0 + i) * 68 + q];
            #pragma unroll
            for (int j = 0; j < 4; ++j) w[j] = *(const float4*)&w2s[(c0 + j) * 68 + q];
            #pragma unroll
            for (int i = 0; i < 4; ++i)
                #pragma unroll
                for (int j = 0; j < 4; ++j) {
                    acc[i][j] = fmaf(a[i].x, w[j].x, acc[i][j]);
                    acc[i][j] = fmaf(a[i].y, w[j].y, acc[i][j]);
                    acc[i][j] = fmaf(a[i].z, w[j].z, acc[i][j]);
                    acc[i][j] = fmaf(a[i].w, w[j].w, acc[i][j]);
                }
        }
        #pragma unroll
        for (int i = 0; i < 4; ++i)
            #pragma unroll
            for (int j = 0; j < 4; ++j)
                h2s[(r0 + i) * 68 + c0 + j] = fmaxf(acc[i][j], 0.f);
    }
    __syncthreads();

    for (int o = t; o < 1024; o += 256) {
        const int p = o >> 6, c = o & 63;
        float m = h2s[(p * 5) * 68 + c];
        #pragma unroll
        for (int k = 1; k < 5; ++k) m = fmaxf(m, h2s[(p * 5 + k) * 68 + c]);
        const unsigned short hi = f2bf(m);
        const size_t co = (size_t)(pbase + p) * 512 + 64 + c;
        catH[co] = hi;
        catL[co] = f2bf(m - bf2f(hi));
    }
    for (int o = t; o < 5120; o += 256) {
        const int r = o >> 6, c = o & 63;
        const float v = h2s[r * 68 + c];
        const unsigned short hi = f2bf(v);
        const size_t rowb = (size_t)(pbase * 5 + r) * 128;
        h2HL[rowb + c]      = hi;
        h2HL[rowb + 64 + c] = f2bf(v - bf2f(hi));
    }
}

// ---------------------------------------------------------------------------
// Kernel B2: FUSED L3+L4 (64->128->256) via split-bf16 MFMA + x3max + x4max.
// mlp4's A-tile for block bx IS mlp3's output tile (both R0 = 80*bx), so h3
// never touches global memory: phase 1 = mlp3 MFMA (h2*w3 -> acc3); phase 2
// = acc3 relu'd to bf16 hi/lo in LDS a2H/a2L [80][136] (mlp4's A layout;
// x3max epilogue reads hi+lo -> bit-identical to the unfused path); phase 3
// = mlp4 ks-loop for BOTH ny halves from the LDS tile; phase 4 = banded
// Dbuf epilogues for x4max. Saves the 84MB h3 write + 168MB re-read and
// 2048 block launches. LDS peak 64000B (2 blocks/CU, as old mlp4).
// ---------------------------------------------------------------------------
__global__ __launch_bounds__(256) void mlp34_kernel(
        const unsigned short* __restrict__ h2HL,
        const unsigned short* __restrict__ w3H, const unsigned short* __restrict__ w3L,
        const unsigned short* __restrict__ w4H, const unsigned short* __restrict__ w4L,
        unsigned short* __restrict__ catH, unsigned short* __restrict__ catL) {
    __shared__ __align__(16) char smem[64000];
    // phase 1: aH[80][72]@0, aL@11520, bH3[128][72]@23040, bL3@41472 (59904)
    // phase 2/3: a2H[80][136]@0 (21760B), a2L@21760, bH4[128][40]@43520,
    //            bL4@53760 (64000)
    // phase 4: Dbuf[80][132] fp32 @0 (42240; a2 dead)
    unsigned short* aH  = (unsigned short*)smem;
    unsigned short* aL  = aH + 80 * 72;
    unsigned short* bH3 = (unsigned short*)(smem + 23040);
    unsigned short* bL3 = (unsigned short*)(smem + 41472);

    const int t = threadIdx.x;
    const int R0 = blockIdx.x * 80;
    const int P0 = blockIdx.x * 16;

    for (int c = t; c < 1280; c += 256) {                  // A: h2 hi|lo rows
        const int row = c >> 4, seg = c & 15;
        const uint4 v = *(const uint4*)(h2HL + (size_t)(R0 + row) * 128 + seg * 8);
        *(uint4*)((seg < 8 ? aH : aL) + row * 72 + (seg & 7) * 8) = v;
    }
    for (int c = t; c < 1024; c += 256) {                  // w3 hi
        const int row = c >> 3, seg = c & 7;
        *(uint4*)(bH3 + row * 72 + seg * 8) =
            *(const uint4*)(w3H + row * 64 + seg * 8);
    }
    for (int c = t; c < 1024; c += 256) {                  // w3 lo
        const int row = c >> 3, seg = c & 7;
        *(uint4*)(bL3 + row * 72 + seg * 8) =
            *(const uint4*)(w3L + row * 64 + seg * 8);
    }
    __syncthreads();

    const int w = t >> 6, lane = t & 63;
    const int q = lane >> 4, l16 = lane & 15;
    const int n0 = w * 32;

    // ---- phase 1: L3 MFMA (64->128) ----
    f32x4 acc3[5][2];
    #pragma unroll
    for (int mt = 0; mt < 5; ++mt)
        #pragma unroll
        for (int nt = 0; nt < 2; ++nt)
            acc3[mt][nt] = (f32x4){0.f, 0.f, 0.f, 0.f};

    #pragma unroll
    for (int kt = 0; kt < 2; ++kt) {
        const int k0 = kt * 32 + q * 8;
        bf16x8 bh[2], bl[2];
        #pragma unroll
        for (int nt = 0; nt < 2; ++nt) {
            bh[nt] = *(const bf16x8*)(bH3 + (n0 + nt * 16 + l16) * 72 + k0);
            bl[nt] = *(const bf16x8*)(bL3 + (n0 + nt * 16 + l16) * 72 + k0);
        }
        #pragma unroll
        for (int mt = 0; mt < 5; ++mt) {
            const bf16x8 ah = *(const bf16x8*)(aH + (mt * 16 + l16) * 72 + k0);
            const bf16x8 al = *(const bf16x8*)(aL + (mt * 16 + l16) * 72 + k0);
            #pragma unroll
            for (int nt = 0; nt < 2; ++nt) {
                acc3[mt][nt] = MFMA16(ah, bh[nt], acc3[mt][nt]);
                acc3[mt][nt] = MFMA16(ah, bl[nt], acc3[mt][nt]);
                acc3[mt][nt] = MFMA16(al, bh[nt], acc3[mt][nt]);
            }
        }
    }

    // ---- phase 2: acc3 -> LDS h3 tile (bf16 hi/lo) + x3max ----
    __syncthreads();                       // phase-1 staging dead
    unsigned short* a2H = (unsigned short*)smem;           // [80][136]
    unsigned short* a2L = a2H + 80 * 136;                  // @21760B
    #pragma unroll
    for (int mt = 0; mt < 5; ++mt)
        #pragma unroll
        for (int nt = 0; nt < 2; ++nt)
            #pragma unroll
            for (int r = 0; r < 4; ++r) {
                const int row = mt * 16 + q * 4 + r;
                const int col = n0 + nt * 16 + l16;
                const float v = fmaxf(acc3[mt][nt][r], 0.f);
                const unsigned short hi = f2bf(v);
                a2H[row * 136 + col] = hi;
                a2L[row * 136 + col] = f2bf(v - bf2f(hi));
            }
    __syncthreads();
    {
        const int col = t & 127;
        const int p0 = (t >> 7) * 8;
        #pragma unroll
        for (int p = 0; p < 8; ++p) {
            const int pp = p0 + p;
            float mx = 0.f;
            #pragma unroll
            for (int k = 0; k < 5; ++k) {
                const int row = pp * 5 + k;
                const float v = bf2f(a2H[row * 136 + col]) +
                                bf2f(a2L[row * 136 + col]);
                mx = fmaxf(mx, v);
            }
            const unsigned short mh = f2bf(mx);
            const size_t co = (size_t)(P0 + pp) * 512 + 128 + col;
            catH[co] = mh;
            catL[co] = f2bf(mx - bf2f(mh));
        }
    }

    // ---- phase 3: L4 MFMA (128->256), both cout halves from LDS tile ----
    unsigned short* bH4 = (unsigned short*)(smem + 43520); // [128][40]
    unsigned short* bL4 = (unsigned short*)(smem + 53760);
    f32x4 acc4[2][5][2];
    #pragma unroll
    for (int ny = 0; ny < 2; ++ny)
        #pragma unroll
        for (int mt = 0; mt < 5; ++mt)
            #pragma unroll
            for (int nt = 0; nt < 2; ++nt)
                acc4[ny][mt][nt] = (f32x4){0.f, 0.f, 0.f, 0.f};

    #pragma unroll
    for (int ny = 0; ny < 2; ++ny) {
        for (int ks = 0; ks < 4; ++ks) {
            __syncthreads();               // WAR on bH4/bL4 (and a2 epilogue)
            #pragma unroll
            for (int i = 0; i < 2; ++i) {  // w4 hi: 512 chunks
                const int c = t + i * 256;
                const int row = c >> 2, seg = c & 3;
                *(uint4*)(bH4 + row * 40 + seg * 8) =
                    *(const uint4*)(w4H + (size_t)(ny * 128 + row) * 128 + ks * 32 + seg * 8);
            }
            #pragma unroll
            for (int i = 0; i < 2; ++i) {  // w4 lo
                const int c = t + i * 256;
                const int row = c >> 2, seg = c & 3;
                *(uint4*)(bL4 + row * 40 + seg * 8) =
                    *(const uint4*)(w4L + (size_t)(ny * 128 + row) * 128 + ks * 32 + seg * 8);
            }
            __syncthreads();

            const int k0 = ks * 32 + q * 8;
            const int kb = q * 8;
            bf16x8 bh[2], bl[2];
            #pragma unroll
            for (int nt = 0; nt < 2; ++nt) {
                bh[nt] = *(const bf16x8*)(bH4 + (n0 + nt * 16 + l16) * 40 + kb);
                bl[nt] = *(const bf16x8*)(bL4 + (n0 + nt * 16 + l16) * 40 + kb);
            }
            #pragma unroll
            for (int mt = 0; mt < 5; ++mt) {
                const bf16x8 ah = *(const bf16x8*)(a2H + (mt * 16 + l16) * 136 + k0);
                const bf16x8 al = *(const bf16x8*)(a2L + (mt * 16 + l16) * 136 + k0);
                #pragma unroll
                for (int nt = 0; nt < 2; ++nt) {
                    acc4[ny][mt][nt] = MFMA16(ah, bh[nt], acc4[ny][mt][nt]);
                    acc4[ny][mt][nt] = MFMA16(ah, bl[nt], acc4[ny][mt][nt]);
                    acc4[ny][mt][nt] = MFMA16(al, bh[nt], acc4[ny][mt][nt]);
                }
            }
        }
    }

    // ---- phase 4: x4max epilogues (a2 dead; Dbuf aliases it) ----
    float* Dbuf = (float*)smem;            // [80][132] fp32
    #pragma unroll
    for (int ny = 0; ny < 2; ++ny) {
        __syncthreads();                   // a2/bH4 reads (or prev epilogue) done
        #pragma unroll
        for (int mt = 0; mt < 5; ++mt)
            #pragma unroll
            for (int nt = 0; nt < 2; ++nt)
                #pragma unroll
                for (int r = 0; r < 4; ++r)
                    Dbuf[(mt * 16 + q * 4 + r) * 132 + n0 + nt * 16 + l16] =
                        fmaxf(acc4[ny][mt][nt][r], 0.f);
        __syncthreads();
        {
            const int col = t & 127;
            const int p0 = (t >> 7) * 8;
            const int cout = 256 + ny * 128 + col;
            #pragma unroll
            for (int p = 0; p < 8; ++p) {
                const int pp = p0 + p;
                float mx = 0.f;
                #pragma unroll
                for (int k = 0; k < 5; ++k)
                    mx = fmaxf(mx, Dbuf[(pp * 5 + k) * 132 + col]);
                const unsigned short mh = f2bf(mx);
                const size_t co = (size_t)(P0 + pp) * 512 + cout;
                catH[co] = mh;
                catL[co] = f2bf(mx - bf2f(mh));
            }
        }
    }
}

// ---------------------------------------------------------------------------
// Kernel D: final GEMM out = relu(cat(32768x512) * W5^T), split-bf16 MFMA.
// Staging via global_load_lds width=16, full-tile coverage: wave w stages
// rows 32w..32w+31 (2KB/tile) in two 16-row halves. Linear [128][32]-short
// tiles; LDS dest wave-uniform + lane*16; global source per-lane.
// ---------------------------------------------------------------------------
__global__ __launch_bounds__(256) void gemm512_kernel(
        const unsigned short* __restrict__ catH, const unsigned short* __restrict__ catL,
        const unsigned short* __restrict__ w5H, const unsigned short* __restrict__ w5L,
        float* __restrict__ out) {
    __shared__ __align__(16) char smem[32768];
    unsigned short* aH = (unsigned short*)smem;            // [128][32] @0 (8KB)
    unsigned short* aL = aH + 128 * 32;                    // @8192
    unsigned short* bH = (unsigned short*)(smem + 16384);  // [128][32]
    unsigned short* bL = (unsigned short*)(smem + 24576);

    const int t = threadIdx.x;
    const int m0 = blockIdx.x * 128;
    const int n0blk = blockIdx.y * 128;

    const int w = t >> 6, lane = t & 63;
    const int q = lane >> 4, l16 = lane & 15;
    const int m_off = (w >> 1) * 64;
    const int n_off = (w & 1) * 64;

    // staging: wave w stages rows 32w..32w+31 (2KB/tile) in two halves.
    const int srow = w * 32 + (lane >> 2);   // first-half row
    const int sseg = lane & 3;
    const size_t ar0 = (size_t)(m0 + srow) * 512 + sseg * 8;
    const size_t ar1 = ar0 + 16 * 512;       // row + 16
    const size_t br0 = (size_t)(n0blk + srow) * 512 + sseg * 8;
    const size_t br1 = br0 + 16 * 512;
    const int ld0 = w * 1024;                // shorts; +512 = second half

    f32x4 acc[4][4];
    #pragma unroll
    for (int mt = 0; mt < 4; ++mt)
        #pragma unroll
        for (int nt = 0; nt < 4; ++nt)
            acc[mt][nt] = (f32x4){0.f, 0.f, 0.f, 0.f};

    for (int kc = 0; kc < 512; kc += 32) {
        __syncthreads();                 // WAR: previous chunk's reads done
        gload16(catH + ar0 + kc, aH + ld0);
        gload16(catH + ar1 + kc, aH + ld0 + 512);
        gload16(catL + ar0 + kc, aL + ld0);
        gload16(catL + ar1 + kc, aL + ld0 + 512);
        gload16(w5H + br0 + kc, bH + ld0);
        gload16(w5H + br1 + kc, bH + ld0 + 512);
        gload16(w5L + br0 + kc, bL + ld0);
        gload16(w5L + br1 + kc, bL + ld0 + 512);
        __syncthreads();                 // drains vmcnt -> staged data visible

        const int k0 = q * 8;
        bf16x8 bh[4], bl[4];
        #pragma unroll
        for (int nt = 0; nt < 4; ++nt) {
            bh[nt] = *(const bf16x8*)(bH + (n_off + nt * 16 + l16) * 32 + k0);
            bl[nt] = *(const bf16x8*)(bL + (n_off + nt * 16 + l16) * 32 + k0);
        }
        #pragma unroll
        for (int mt = 0; mt < 4; ++mt) {
            const bf16x8 ah = *(const bf16x8*)(aH + (m_off + mt * 16 + l16) * 32 + k0);
            const bf16x8 al = *(const bf16x8*)(aL + (m_off + mt * 16 + l16) * 32 + k0);
            #pragma unroll
            for (int nt = 0; nt < 4; ++nt) {
                acc[mt][nt] = MFMA16(ah, bh[nt], acc[mt][nt]);
                acc[mt][nt] = MFMA16(ah, bl[nt], acc[mt][nt]);
                acc[mt][nt] = MFMA16(al, bh[nt], acc[mt][nt]);
            }
        }
    }

    // band-wise epilogue: 8 bands of 16 rows; LDS transpose for coalesced out
    float* bandbuf = (float*)smem;         // [16][132] fp32 (8448B <= 32KB)
    for (int b8 = 0; b8 < 8; ++b8) {
        __syncthreads();
        if ((w >> 1) == (b8 >> 2)) {
            const int mt = b8 & 3;
            #pragma unroll
            for (int nt = 0; nt < 4; ++nt)
                #pragma unroll
                for (int r = 0; r < 4; ++r)
                    bandbuf[(q * 4 + r) * 132 + n_off + nt * 16 + l16] =
                        fmaxf(acc[mt][nt][r], 0.f);
        }
        __syncthreads();
        const int col = t >> 1;
        const int ph = (t & 1) * 8;
        const int P = m0 + b8 * 16 + ph;
        const int bb = P >> 13, nn = P & 8191;
        const int cout = n0blk + col;
        float tmp[8];
        #pragma unroll
        for (int j = 0; j < 8; ++j) tmp[j] = bandbuf[(ph + j) * 132 + col];
        float* op = &out[((size_t)bb * 512 + cout) * NPTS + nn];
        *(float4*)op       = make_float4(tmp[0], tmp[1], tmp[2], tmp[3]);
        *(float4*)(op + 4) = make_float4(tmp[4], tmp[5], tmp[6], tmp[7]);
    }
}

extern "C" void kernel_launch(void* const* d_in, const int* in_sizes, int n_in,
                              void* d_out, int out_size, void* d_ws, size_t ws_size,
                              hipStream_t stream) {
    (void)in_sizes; (void)n_in; (void)out_size; (void)ws_size;
    const float* x  = (const float*)d_in[0];
    const float* w1 = (const float*)d_in[1];
    const float* w2 = (const float*)d_in[2];
    const float* w3 = (const float*)d_in[3];
    const float* w4 = (const float*)d_in[4];
    const float* w5 = (const float*)d_in[5];
    float* out = (float*)d_out;

    // workspace layout (h3 eliminated by mlp34 fusion; ~69.3 MB used)
    char* ws = (char*)d_ws;
    unsigned short* w3H = (unsigned short*)(ws + 0);          //  16384 B
    unsigned short* w3L = (unsigned short*)(ws + 16384);
    unsigned short* w4H = (unsigned short*)(ws + 32768);      //  65536 B
    unsigned short* w4L = (unsigned short*)(ws + 98304);
    unsigned short* w5H = (unsigned short*)(ws + 163840);     // 524288 B
    unsigned short* w5L = (unsigned short*)(ws + 688128);
    int*            idx = (int*)(ws + 1212416);               // 655360 B
    unsigned short* catH = (unsigned short*)(ws + 2097152);   // 33.55 MB
    unsigned short* catL = (unsigned short*)(ws + 35651584);  // 33.55 MB
    float*          c2d  = (float*)(ws + 69206016);           // 131072 B
    // d_out doubles as scratch for h2 (hi|lo interleaved)
    unsigned short* h2HL = (unsigned short*)d_out;

    wsplit_kernel<<<dim3(1312), dim3(256), 0, stream>>>(w3, w4, w5, x,
                                                        w3H, w3L, w4H, w4L, w5H, w5L,
                                                        c2d);
    knn_kernel<<<dim3(BATCH * NPTS / 64), dim3(1024), 0, stream>>>(x, c2d, idx);
    mlp12_kernel<<<dim3(BATCH * NPTS / 16), dim3(256), 0, stream>>>(x, idx, w1, w2,
                                                                    h2HL, catH, catL);
    mlp34_kernel<<<dim3(BATCH * NPTS * KNN / 80), dim3(256), 0, stream>>>(
        h2HL, w3H, w3L, w4H, w4L, catH, catL);
    gemm512_kernel<<<dim3(BATCH * NPTS / 128, 4), dim3(256), 0, stream>>>(
        catH, catL, w5H, w5L, out);
}